// Round 11
// baseline (3585.059 us; speedup 1.0000x reference)
//
#include <hip/hip_runtime.h>
#include <hip/hip_bf16.h>

#define LL 8
#define BBx 4
#define TT 2048
#define CC 1024
#define HH 16
#define HDD 64
#define DFFx 4096
#define MMx 8192  // B*T

typedef __bf16 bf16;
typedef __attribute__((ext_vector_type(8))) __bf16 bf16x8;
typedef __attribute__((ext_vector_type(4))) __bf16 bf16x4;
typedef __attribute__((ext_vector_type(4))) float f32x4;
typedef __attribute__((ext_vector_type(8))) unsigned short u16x8;

#define QSCALE 0.18033688f  // 0.125 * log2(e): Q pre-scaled -> softmax in exp2 domain

__device__ __forceinline__ unsigned short bfbits(float v) {
  return __builtin_bit_cast(unsigned short, (__bf16)v);
}

// XCD-chunked bijective swizzle (T1): nwg % 8 == 0 required.
__device__ __forceinline__ int xcd_swz(int id, int nwg) {
  return (id & 7) * (nwg >> 3) + (id >> 3);
}

#define GLDS(gp, lp) __builtin_amdgcn_global_load_lds( \
    (const __attribute__((address_space(1))) void*)(gp), \
    (__attribute__((address_space(3))) void*)(lp), 16, 0, 0)

// ---------- weight transpose + cast:  W[z][K][N] fp32 -> Wt[z][N][K] bf16 ----------
__global__ __launch_bounds__(256) void transpose_cast(
    const float* __restrict__ W, bf16* __restrict__ Wt,
    int K, int N, long srcStride, long dstStride)
{
  __shared__ float tile[32][33];
  const float* Wl = W + (size_t)blockIdx.z * srcStride;
  bf16* Wtl = Wt + (size_t)blockIdx.z * dstStride;
  const int n0 = blockIdx.x * 32, k0 = blockIdx.y * 32;
  const int tx = threadIdx.x, ty = threadIdx.y;
#pragma unroll
  for (int i = 0; i < 32; i += 8)
    tile[ty + i][tx] = Wl[(size_t)(k0 + ty + i) * N + n0 + tx];
  __syncthreads();
#pragma unroll
  for (int i = 0; i < 32; i += 8)
    Wtl[(size_t)(n0 + ty + i) * K + k0 + tx] = (bf16)tile[tx][ty + i];
}

// ---------- layernorm fp32 -> bf16 (one block per row, C=1024) ----------
__global__ __launch_bounds__(256) void ln_fwd(
    const float* __restrict__ h, const float* __restrict__ gamma,
    const float* __restrict__ beta, bf16* __restrict__ out)
{
  const int row = blockIdx.x, tid = threadIdx.x;
  const float4 v = *(const float4*)(h + (size_t)row * CC + tid * 4);
  float s  = v.x + v.y + v.z + v.w;
  float ss = v.x * v.x + v.y * v.y + v.z * v.z + v.w * v.w;
#pragma unroll
  for (int o = 32; o >= 1; o >>= 1) {
    s  += __shfl_xor(s, o);
    ss += __shfl_xor(ss, o);
  }
  __shared__ float rs[4], rss[4];
  const int w = tid >> 6, l = tid & 63;
  if (l == 0) { rs[w] = s; rss[w] = ss; }
  __syncthreads();
  s  = rs[0] + rs[1] + rs[2] + rs[3];
  ss = rss[0] + rss[1] + rss[2] + rss[3];
  const float mu = s * (1.f / CC);
  const float rstd = rsqrtf(ss * (1.f / CC) - mu * mu + 1e-5f);
  const float4 g  = *(const float4*)(gamma + tid * 4);
  const float4 be = *(const float4*)(beta + tid * 4);
  bf16x4 o4;
  o4[0] = (bf16)((v.x - mu) * rstd * g.x + be.x);
  o4[1] = (bf16)((v.y - mu) * rstd * g.y + be.y);
  o4[2] = (bf16)((v.z - mu) * rstd * g.z + be.z);
  o4[3] = (bf16)((v.w - mu) * rstd * g.w + be.w);
  *(bf16x4*)(out + (size_t)row * CC + tid * 4) = o4;
}

// ---------- 128x128 GEMM, m97 structure: single-buffer, 2 barriers/K-tile ----------
// 256 thr = 4 waves (2M x 2N), wave tile 64x64, 32 KB LDS -> ~4 blocks/CU.
// 1D grid, XCD-chunked swizzle. j-innermost line-complete stores.
// EPI 0: fused QKV (q pre-scaled by QSCALE); EPI 1: direct fp32 residual
// accumulate (single writer, no atomics); EPI 2: GELU.
template<int EPI>
__global__ __launch_bounds__(256, 4) void gemm128(
    const bf16* __restrict__ A, const bf16* __restrict__ Bt,
    const float* __restrict__ bias0, const float* __restrict__ bias1,
    const float* __restrict__ bias2,
    bf16* __restrict__ o0, bf16* __restrict__ o1, bf16* __restrict__ o2,
    float* __restrict__ resid, int M, int N, int K)
{
  __shared__ __align__(16) bf16 sA[128 * 64];
  __shared__ __align__(16) bf16 sB[128 * 64];
  const int nx = N >> 7;
  const int wk = xcd_swz((int)blockIdx.x, (int)gridDim.x);
  const int m0 = (wk / nx) * 128;
  const int n0 = (wk % nx) * 128;
  const int tid = threadIdx.x;
  const int w = tid >> 6, l = tid & 63;
  const int wr = w >> 1, wc = w & 1;
  const int lr = l & 15, lk = l >> 4;

  f32x4 acc[4][4] = {};
  const int NT = K >> 6;

  for (int kt = 0; kt < NT; ++kt) {
#pragma unroll
    for (int i = 0; i < 4; ++i) {
      const int e = (tid << 4) + (i << 12);   // linear LDS byte offset
      const int ro = e >> 7, co = (e & 127) >> 1;
      GLDS(A + (size_t)(m0 + ro) * K + kt * 64 + co, sA + (e >> 1));
      GLDS(Bt + (size_t)(n0 + ro) * K + kt * 64 + co, sB + (e >> 1));
    }
    __syncthreads();
#pragma unroll
    for (int kk = 0; kk < 2; ++kk) {
      bf16x8 af[4], bfr[4];
#pragma unroll
      for (int i = 0; i < 4; ++i)
        af[i] = *(const bf16x8*)&sA[(wr * 64 + i * 16 + lr) * 64 + kk * 32 + lk * 8];
#pragma unroll
      for (int j = 0; j < 4; ++j)
        bfr[j] = *(const bf16x8*)&sB[(wc * 64 + j * 16 + lr) * 64 + kk * 32 + lk * 8];
#pragma unroll
      for (int i = 0; i < 4; ++i)
#pragma unroll
        for (int j = 0; j < 4; ++j)
          acc[i][j] = __builtin_amdgcn_mfma_f32_16x16x32_bf16(af[i], bfr[j], acc[i][j], 0, 0, 0);
    }
    __syncthreads();
  }

  if constexpr (EPI == 0) {
    const int seg = n0 >> 10;
    const float* bp = (seg == 0) ? bias0 : (seg == 1 ? bias1 : bias2);
    if (seg < 2) {
      const float qs = (seg == 0) ? QSCALE : 1.0f;   // pre-scale q for exp2 softmax
      float bv4[4];
#pragma unroll
      for (int j = 0; j < 4; ++j) bv4[j] = bp[(n0 + wc * 64 + j * 16 + lr) & 1023];
      const int hh = ((n0 + wc * 64) & 1023) >> 6;
      bf16* dst = (seg == 0) ? o0 : o1;
#pragma unroll
      for (int i = 0; i < 4; ++i) {
        const int mrow = m0 + wr * 64 + i * 16 + lk * 4;
        const int bidx = mrow >> 11, t = mrow & 2047;
#pragma unroll
        for (int r = 0; r < 4; ++r) {
          bf16* rowp = dst + (((size_t)(bidx * HH + hh)) * TT + t + r) * HDD;
#pragma unroll
          for (int j = 0; j < 4; ++j)   // 4 x 32B chunks back-to-back = full 128B line
            rowp[j * 16 + lr] = (bf16)((acc[i][j][r] + bv4[j]) * qs);
        }
      }
    } else {
      // v: LDS-bounce transpose -> coalesced [b][h][d][t] stores.
      // Wave-private 8 KB scratch ([64 d][64 t] bf16, 128B rows, 16B-XOR swizzle).
      char* scb = (w < 2) ? ((char*)sA + w * 8192) : ((char*)sB + (w - 2) * 8192);
#pragma unroll
      for (int j = 0; j < 4; ++j) {
        const int dl = j * 16 + lr;                  // local d 0..63
        const float bv = bias2[(n0 + wc * 64 + dl) & 1023];
#pragma unroll
        for (int i = 0; i < 4; ++i) {
          ushort4 pk;
          pk.x = bfbits(acc[i][j][0] + bv);
          pk.y = bfbits(acc[i][j][1] + bv);
          pk.z = bfbits(acc[i][j][2] + bv);
          pk.w = bfbits(acc[i][j][3] + bv);
          *(ushort4*)(scb + dl * 128 + (((i * 16 + lk * 4) * 2) ^ ((dl & 7) << 4))) = pk;
        }
      }
      asm volatile("s_waitcnt lgkmcnt(0)" ::: "memory");
      const int hh = ((n0 + wc * 64) & 1023) >> 6;   // one head per wave
      const int bidx = (m0 + wr * 64) >> 11;
      const int tb = (m0 + wr * 64) & 2047;
      const int c = l & 7;                           // 8-elem t-chunk within 64
#pragma unroll
      for (int g = 0; g < 8; ++g) {
        const int dl = g * 8 + (l >> 3);
        u16x8 val = *(const u16x8*)(scb + dl * 128 + ((c * 16) ^ ((dl & 7) << 4)));
        *(u16x8*)&o2[(((size_t)(bidx * HH + hh)) * HDD + dl) * TT + tb + c * 8] = val;
      }
    }
  } else if constexpr (EPI == 1) {
    float bv4[4];
#pragma unroll
    for (int j = 0; j < 4; ++j) bv4[j] = bias0[n0 + wc * 64 + j * 16 + lr];
#pragma unroll
    for (int i = 0; i < 4; ++i) {
      const int mrow = m0 + wr * 64 + i * 16 + lk * 4;
#pragma unroll
      for (int r = 0; r < 4; ++r) {
        float* rowp = resid + (size_t)(mrow + r) * N + n0 + wc * 64;
#pragma unroll
        for (int j = 0; j < 4; ++j)   // single-writer RMW, line-local
          rowp[j * 16 + lr] += acc[i][j][r] + bv4[j];
      }
    }
  } else {  // EPI == 2: GELU
    float bv4[4];
#pragma unroll
    for (int j = 0; j < 4; ++j) bv4[j] = bias0[n0 + wc * 64 + j * 16 + lr];
#pragma unroll
    for (int i = 0; i < 4; ++i) {
      const int mrow = m0 + wr * 64 + i * 16 + lk * 4;
#pragma unroll
      for (int r = 0; r < 4; ++r) {
        bf16* rowp = o0 + (size_t)(mrow + r) * N + n0 + wc * 64;
#pragma unroll
        for (int j = 0; j < 4; ++j) {
          const float x = acc[i][j][r] + bv4[j];
          rowp[j * 16 + lr] = (bf16)(0.5f * x * (1.f + erff(x * 0.70710678f)));
        }
      }
    }
  }
  (void)M;
}

// ---------- causal flash attention (R9 staging; exp2-domain softmax) ----------
// Q,K: [b][h][t][d] (Q pre-scaled by 0.125*log2e); Vt: [b][h][d][t]; O bf16.
// 1D grid of 512, XCD-swizzled. Block = 4 waves x 32 q-rows, pair {xt, 15-xt}.
// Masking applied only on the single diagonal tile per (wave,qi).
__global__ __launch_bounds__(256) void attn_fwd(
    const bf16* __restrict__ Q, const bf16* __restrict__ Kk,
    const bf16* __restrict__ Vt, bf16* __restrict__ O)
{
  const int wk = xcd_swz((int)blockIdx.x, (int)gridDim.x);
  const int bh = wk >> 3;
  const int xt = wk & 7;
  const int tid = threadIdx.x;
  const int w = tid >> 6, l = tid & 63;
  const int lr = l & 15, lk = l >> 4;
  const int bidx = bh >> 4, hh = bh & 15;

  const bf16* Qp = Q  + (size_t)bh * (TT * HDD);
  const bf16* Kp = Kk + (size_t)bh * (TT * HDD);
  const bf16* Vp = Vt + (size_t)bh * (HDD * TT);

  __shared__ __align__(16) bf16 sK[64 * 64];
  __shared__ __align__(16) bf16 sV[64 * 64];
  __shared__ __align__(16) bf16 sP[4][16 * 64];
  bf16* sPw = &sP[w][0];

  const int swz = (lr & 7) * 8;       // element-offset XOR for LDS reads
  const int srow = tid >> 3;                        // staging source row 0..31
  const int scol = (((tid & 7) ^ (srow & 7)) << 3); // inverse-swizzled source col
  const int sdst = tid << 3;                        // linear LDS dest (elements)

  for (int half = 0; half < 2; ++half) {
    const int qtile = (half == 0) ? xt : (15 - xt);
    const int q0 = qtile * 128;

    bf16x8 qf[2][2];
#pragma unroll
    for (int qi = 0; qi < 2; ++qi)
#pragma unroll
      for (int dk = 0; dk < 2; ++dk)
        qf[qi][dk] = *(const bf16x8*)&Qp[(size_t)(q0 + w * 32 + qi * 16 + lr) * HDD + dk * 32 + lk * 8];

    f32x4 accO[2][4] = {};
    float mrun[2] = {-__builtin_inff(), -__builtin_inff()};
    float lrun[2] = {0.f, 0.f};
    const int wqmax = q0 + w * 32 + 31;
    const int kvend = q0 + 128;

    for (int kv = 0; kv < kvend; kv += 64) {
      __syncthreads();   // previous LDS readers done (and half-boundary safety)
#pragma unroll
      for (int i = 0; i < 2; ++i) {
        GLDS(Kp + (size_t)(kv + srow + i * 32) * HDD + scol, sK + sdst + i * 2048);
        GLDS(Vp + (size_t)(srow + i * 32) * TT + kv + scol, sV + sdst + i * 2048);
      }
      __syncthreads();   // staging complete

      if (kv <= wqmax) {
#pragma unroll
        for (int qi = 0; qi < 2; ++qi) {
          f32x4 st[4];
#pragma unroll
          for (int kt = 0; kt < 4; ++kt) {
            f32x4 z = {0.f, 0.f, 0.f, 0.f};
#pragma unroll
            for (int dk = 0; dk < 2; ++dk) {
              bf16x8 kf = *(const bf16x8*)&sK[(kt * 16 + lr) * 64 + ((dk * 32 + lk * 8) ^ swz)];
              z = __builtin_amdgcn_mfma_f32_16x16x32_bf16(kf, qf[qi][dk], z, 0, 0, 0);
            }
            st[kt] = z;
          }
          const int qabs_base = q0 + w * 32 + qi * 16;
          float pm = -__builtin_inff();
          if (kv + 63 > qabs_base) {
            // diagonal tile: per-element causal mask (scores already scaled)
            const int qabs = qabs_base + lr;
#pragma unroll
            for (int kt = 0; kt < 4; ++kt)
#pragma unroll
              for (int r = 0; r < 4; ++r) {
                const int kvabs = kv + kt * 16 + lk * 4 + r;
                float val = (kvabs > qabs) ? -__builtin_inff() : st[kt][r];
                st[kt][r] = val;
                pm = fmaxf(pm, val);
              }
          } else {
#pragma unroll
            for (int kt = 0; kt < 4; ++kt)
#pragma unroll
              for (int r = 0; r < 4; ++r) pm = fmaxf(pm, st[kt][r]);
          }
          pm = fmaxf(pm, __shfl_xor(pm, 16));
          pm = fmaxf(pm, __shfl_xor(pm, 32));
          const float mnew = fmaxf(mrun[qi], pm);
          const float alpha = exp2f(mrun[qi] - mnew);
          mrun[qi] = mnew;
          float psum = 0.f;
#pragma unroll
          for (int kt = 0; kt < 4; ++kt) {
            const float p0v = exp2f(st[kt][0] - mnew);
            const float p1v = exp2f(st[kt][1] - mnew);
            const float p2v = exp2f(st[kt][2] - mnew);
            const float p3v = exp2f(st[kt][3] - mnew);
            psum += p0v + p1v + p2v + p3v;
            ushort4 pk;
            pk.x = bfbits(p0v); pk.y = bfbits(p1v); pk.z = bfbits(p2v); pk.w = bfbits(p3v);
            *(ushort4*)&sPw[lr * 64 + ((kt * 16 + lk * 4) ^ swz)] = pk;
          }
          psum += __shfl_xor(psum, 16);
          psum += __shfl_xor(psum, 32);
          lrun[qi] = lrun[qi] * alpha + psum;
          f32x4 al4;
#pragma unroll
          for (int r = 0; r < 4; ++r) al4[r] = __shfl(alpha, lk * 4 + r);
#pragma unroll
          for (int dj = 0; dj < 4; ++dj) accO[qi][dj] *= al4;
#pragma unroll
          for (int kt2 = 0; kt2 < 2; ++kt2) {
            bf16x8 pf = *(const bf16x8*)&sPw[lr * 64 + ((kt2 * 32 + lk * 8) ^ swz)];
#pragma unroll
            for (int dj = 0; dj < 4; ++dj) {
              bf16x8 vf = *(const bf16x8*)&sV[(dj * 16 + lr) * 64 + ((kt2 * 32 + lk * 8) ^ swz)];
              accO[qi][dj] = __builtin_amdgcn_mfma_f32_16x16x32_bf16(pf, vf, accO[qi][dj], 0, 0, 0);
            }
          }
        }
      }
    }

#pragma unroll
    for (int qi = 0; qi < 2; ++qi) {
      const float linv = 1.f / lrun[qi];
      f32x4 li4;
#pragma unroll
      for (int r = 0; r < 4; ++r) li4[r] = __shfl(linv, lk * 4 + r);
      const int tbase = q0 + w * 32 + qi * 16 + lk * 4;
#pragma unroll
      for (int dj = 0; dj < 4; ++dj)
#pragma unroll
        for (int r = 0; r < 4; ++r)
          O[((size_t)bidx * TT + tbase + r) * CC + hh * 64 + dj * 16 + lr] =
              (bf16)(accO[qi][dj][r] * li4[r]);
    }
  }
}

extern "C" void kernel_launch(void* const* d_in, const int* in_sizes, int n_in,
                              void* d_out, int out_size, void* d_ws, size_t ws_size,
                              hipStream_t stream)
{
  const float* x    = (const float*)d_in[0];
  const float* ln1g = (const float*)d_in[1];
  const float* ln1b = (const float*)d_in[2];
  const float* ln2g = (const float*)d_in[3];
  const float* ln2b = (const float*)d_in[4];
  const float* wq   = (const float*)d_in[5];
  const float* bq   = (const float*)d_in[6];
  const float* wk   = (const float*)d_in[7];
  const float* bk   = (const float*)d_in[8];
  const float* wv   = (const float*)d_in[9];
  const float* bvv  = (const float*)d_in[10];
  const float* wo   = (const float*)d_in[11];
  const float* bo   = (const float*)d_in[12];
  const float* w1   = (const float*)d_in[13];
  const float* b1   = (const float*)d_in[14];
  const float* w2   = (const float*)d_in[15];
  const float* b2   = (const float*)d_in[16];

  float* h = (float*)d_out;  // fp32 residual stream lives in d_out
  bf16* ws = (bf16*)d_ws;
  bf16* wqkvT = ws;                                   // [L][3][C][C]
  bf16* woT   = wqkvT + (size_t)LL * 3 * CC * CC;     // [L][C][C]
  bf16* w1T   = woT + (size_t)LL * CC * CC;           // [L][DFF][C]
  bf16* w2T   = w1T + (size_t)LL * CC * DFFx;         // [L][C][DFF]
  bf16* hn    = w2T + (size_t)LL * CC * DFFx;         // [M][C]
  bf16* qb    = hn + (size_t)MMx * CC;                // [b][h][t][d]
  bf16* kb    = qb + (size_t)MMx * CC;
  bf16* vt    = kb + (size_t)MMx * CC;                // [b][h][d][t]
  bf16* ab    = vt + (size_t)MMx * CC;                // [b][t][c]
  bf16* mid   = ab + (size_t)MMx * CC;                // [M][DFF]

  hipMemcpyAsync(h, x, (size_t)MMx * CC * sizeof(float), hipMemcpyDeviceToDevice, stream);

  dim3 tb(32, 8);
  transpose_cast<<<dim3(CC / 32, CC / 32, LL), tb, 0, stream>>>(wq, wqkvT, CC, CC, (long)CC * CC, (long)3 * CC * CC);
  transpose_cast<<<dim3(CC / 32, CC / 32, LL), tb, 0, stream>>>(wk, wqkvT + CC * CC, CC, CC, (long)CC * CC, (long)3 * CC * CC);
  transpose_cast<<<dim3(CC / 32, CC / 32, LL), tb, 0, stream>>>(wv, wqkvT + 2 * CC * CC, CC, CC, (long)CC * CC, (long)3 * CC * CC);
  transpose_cast<<<dim3(CC / 32, CC / 32, LL), tb, 0, stream>>>(wo, woT, CC, CC, (long)CC * CC, (long)CC * CC);
  transpose_cast<<<dim3(DFFx / 32, CC / 32, LL), tb, 0, stream>>>(w1, w1T, CC, DFFx, (long)CC * DFFx, (long)CC * DFFx);
  transpose_cast<<<dim3(CC / 32, DFFx / 32, LL), tb, 0, stream>>>(w2, w2T, DFFx, CC, (long)CC * DFFx, (long)CC * DFFx);

  for (int li = 0; li < LL; ++li) {
    ln_fwd<<<MMx, 256, 0, stream>>>(h, ln1g + li * CC, ln1b + li * CC, hn);
    gemm128<0><<<(3 * CC / 128) * (MMx / 128), 256, 0, stream>>>(
        hn, wqkvT + (size_t)li * 3 * CC * CC, bq + li * CC, bk + li * CC, bvv + li * CC,
        qb, kb, vt, nullptr, MMx, 3 * CC, CC);
    attn_fwd<<<8 * BBx * HH, 256, 0, stream>>>(qb, kb, vt, ab);
    gemm128<1><<<(CC / 128) * (MMx / 128), 256, 0, stream>>>(
        ab, woT + (size_t)li * CC * CC, bo + li * CC, nullptr, nullptr,
        nullptr, nullptr, nullptr, h, MMx, CC, CC);
    ln_fwd<<<MMx, 256, 0, stream>>>(h, ln2g + li * CC, ln2b + li * CC, hn);
    gemm128<2><<<(DFFx / 128) * (MMx / 128), 256, 0, stream>>>(
        hn, w1T + (size_t)li * CC * DFFx, b1 + li * DFFx, nullptr, nullptr,
        mid, nullptr, nullptr, nullptr, MMx, DFFx, CC);
    gemm128<1><<<(CC / 128) * (MMx / 128), 256, 0, stream>>>(
        mid, w2T + (size_t)li * CC * DFFx, b2 + li * CC, nullptr, nullptr,
        nullptr, nullptr, nullptr, h, MMx, CC, DFFx);
  }
  (void)in_sizes; (void)n_in; (void)out_size; (void)ws_size;
}

// Round 12
// 3384.544 us; speedup vs baseline: 1.0592x; 1.0592x over previous
//
#include <hip/hip_runtime.h>
#include <hip/hip_bf16.h>

#define LL 8
#define BBx 4
#define TT 2048
#define CC 1024
#define HH 16
#define HDD 64
#define DFFx 4096
#define MMx 8192  // B*T

typedef __bf16 bf16;
typedef __attribute__((ext_vector_type(8))) __bf16 bf16x8;
typedef __attribute__((ext_vector_type(4))) __bf16 bf16x4;
typedef __attribute__((ext_vector_type(4))) float f32x4;
typedef __attribute__((ext_vector_type(8))) unsigned short u16x8;

#define QSCALE 0.18033688f  // 0.125 * log2(e): Q pre-scaled -> softmax in exp2 domain

__device__ __forceinline__ unsigned short bfbits(float v) {
  return __builtin_bit_cast(unsigned short, (__bf16)v);
}

// XCD-chunked bijective swizzle (T1): nwg % 8 == 0 required.
__device__ __forceinline__ int xcd_swz(int id, int nwg) {
  return (id & 7) * (nwg >> 3) + (id >> 3);
}

#define GLDS(gp, lp) __builtin_amdgcn_global_load_lds( \
    (const __attribute__((address_space(1))) void*)(gp), \
    (__attribute__((address_space(3))) void*)(lp), 16, 0, 0)

// ---------- weight transpose + cast:  W[z][K][N] fp32 -> Wt[z][N][K] bf16 ----------
__global__ __launch_bounds__(256) void transpose_cast(
    const float* __restrict__ W, bf16* __restrict__ Wt,
    int K, int N, long srcStride, long dstStride)
{
  __shared__ float tile[32][33];
  const float* Wl = W + (size_t)blockIdx.z * srcStride;
  bf16* Wtl = Wt + (size_t)blockIdx.z * dstStride;
  const int n0 = blockIdx.x * 32, k0 = blockIdx.y * 32;
  const int tx = threadIdx.x, ty = threadIdx.y;
#pragma unroll
  for (int i = 0; i < 32; i += 8)
    tile[ty + i][tx] = Wl[(size_t)(k0 + ty + i) * N + n0 + tx];
  __syncthreads();
#pragma unroll
  for (int i = 0; i < 32; i += 8)
    Wtl[(size_t)(n0 + ty + i) * K + k0 + tx] = (bf16)tile[tx][ty + i];
}

// ---------- layernorm (+ optional split-K combine) fp32 -> bf16 ----------
// h_new = h + p0 + p1 (bias pre-folded into p0); out = LN(h_new) if out != null.
__global__ __launch_bounds__(256) void ln_cmb(
    float* __restrict__ h, const float* __restrict__ p0, const float* __restrict__ p1,
    const float* __restrict__ gamma, const float* __restrict__ beta,
    bf16* __restrict__ out)
{
  const int row = blockIdx.x, tid = threadIdx.x;
  const size_t base = (size_t)row * CC + tid * 4;
  float4 v = *(const float4*)(h + base);
  if (p0) {
    const float4 a = *(const float4*)(p0 + base);
    const float4 b = *(const float4*)(p1 + base);
    v.x += a.x + b.x; v.y += a.y + b.y; v.z += a.z + b.z; v.w += a.w + b.w;
    *(float4*)(h + base) = v;
  }
  if (!out) return;
  float s  = v.x + v.y + v.z + v.w;
  float ss = v.x * v.x + v.y * v.y + v.z * v.z + v.w * v.w;
#pragma unroll
  for (int o = 32; o >= 1; o >>= 1) {
    s  += __shfl_xor(s, o);
    ss += __shfl_xor(ss, o);
  }
  __shared__ float rs[4], rss[4];
  const int w = tid >> 6, l = tid & 63;
  if (l == 0) { rs[w] = s; rss[w] = ss; }
  __syncthreads();
  s  = rs[0] + rs[1] + rs[2] + rs[3];
  ss = rss[0] + rss[1] + rss[2] + rss[3];
  const float mu = s * (1.f / CC);
  const float rstd = rsqrtf(ss * (1.f / CC) - mu * mu + 1e-5f);
  const float4 g  = *(const float4*)(gamma + tid * 4);
  const float4 be = *(const float4*)(beta + tid * 4);
  bf16x4 o4;
  o4[0] = (bf16)((v.x - mu) * rstd * g.x + be.x);
  o4[1] = (bf16)((v.y - mu) * rstd * g.y + be.y);
  o4[2] = (bf16)((v.z - mu) * rstd * g.z + be.z);
  o4[3] = (bf16)((v.w - mu) * rstd * g.w + be.w);
  *(bf16x4*)(out + (size_t)row * CC + tid * 4) = o4;
}

// ---------- 128x128 GEMM, m97 structure: single-buffer, 2 barriers/K-tile ----------
// 256 thr = 4 waves (2M x 2N), wave tile 64x64, 32 KB LDS -> 4 blocks/CU (split-K
// keeps grids >= 1024 so 4 blocks/CU are actually resident; m114 overlap).
// 1D grid, XCD-chunked swizzle. j-innermost line-complete stores.
// EPI 0: fused QKV (q pre-scaled by QSCALE); EPI 1: split-K=2 fp32 partial write;
// EPI 2: GELU.
template<int EPI>
__global__ __launch_bounds__(256, 4) void gemm128(
    const bf16* __restrict__ A, const bf16* __restrict__ Bt,
    const float* __restrict__ bias0, const float* __restrict__ bias1,
    const float* __restrict__ bias2,
    bf16* __restrict__ o0, bf16* __restrict__ o1, bf16* __restrict__ o2,
    float* __restrict__ p0, float* __restrict__ p1,
    int M, int N, int K, int lda)
{
  __shared__ __align__(16) bf16 sA[128 * 64];
  __shared__ __align__(16) bf16 sB[128 * 64];
  const int nx = N >> 7;
  int wk = xcd_swz((int)blockIdx.x, (int)gridDim.x);
  int koff = 0;
  float* part = p0;
  bool addb = true;
  if constexpr (EPI == 1) {
    const int tiles = nx * (M >> 7);
    const int ks = wk / tiles;
    wk -= ks * tiles;
    koff = ks * K;
    addb = (ks == 0);
    part = ks ? p1 : p0;
  }
  const int m0 = (wk / nx) * 128;
  const int n0 = (wk % nx) * 128;
  const int tid = threadIdx.x;
  const int w = tid >> 6, l = tid & 63;
  const int wr = w >> 1, wc = w & 1;
  const int lr = l & 15, lk = l >> 4;

  f32x4 acc[4][4] = {};
  const int NT = K >> 6;

  for (int kt = 0; kt < NT; ++kt) {
#pragma unroll
    for (int i = 0; i < 4; ++i) {
      const int e = (tid << 4) + (i << 12);   // linear LDS byte offset
      const int ro = e >> 7, co = (e & 127) >> 1;
      GLDS(A + (size_t)(m0 + ro) * lda + kt * 64 + koff + co, sA + (e >> 1));
      GLDS(Bt + (size_t)(n0 + ro) * lda + kt * 64 + koff + co, sB + (e >> 1));
    }
    __syncthreads();
#pragma unroll
    for (int kk = 0; kk < 2; ++kk) {
      bf16x8 af[4], bfr[4];
#pragma unroll
      for (int i = 0; i < 4; ++i)
        af[i] = *(const bf16x8*)&sA[(wr * 64 + i * 16 + lr) * 64 + kk * 32 + lk * 8];
#pragma unroll
      for (int j = 0; j < 4; ++j)
        bfr[j] = *(const bf16x8*)&sB[(wc * 64 + j * 16 + lr) * 64 + kk * 32 + lk * 8];
#pragma unroll
      for (int i = 0; i < 4; ++i)
#pragma unroll
        for (int j = 0; j < 4; ++j)
          acc[i][j] = __builtin_amdgcn_mfma_f32_16x16x32_bf16(af[i], bfr[j], acc[i][j], 0, 0, 0);
    }
    __syncthreads();
  }

  if constexpr (EPI == 0) {
    const int seg = n0 >> 10;
    const float* bp = (seg == 0) ? bias0 : (seg == 1 ? bias1 : bias2);
    if (seg < 2) {
      const float qs = (seg == 0) ? QSCALE : 1.0f;   // pre-scale q for exp2 softmax
      float bv4[4];
#pragma unroll
      for (int j = 0; j < 4; ++j) bv4[j] = bp[(n0 + wc * 64 + j * 16 + lr) & 1023];
      const int hh = ((n0 + wc * 64) & 1023) >> 6;
      bf16* dst = (seg == 0) ? o0 : o1;
#pragma unroll
      for (int i = 0; i < 4; ++i) {
        const int mrow = m0 + wr * 64 + i * 16 + lk * 4;
        const int bidx = mrow >> 11, t = mrow & 2047;
#pragma unroll
        for (int r = 0; r < 4; ++r) {
          bf16* rowp = dst + (((size_t)(bidx * HH + hh)) * TT + t + r) * HDD;
#pragma unroll
          for (int j = 0; j < 4; ++j)   // 4 x 32B chunks back-to-back = full 128B line
            rowp[j * 16 + lr] = (bf16)((acc[i][j][r] + bv4[j]) * qs);
        }
      }
    } else {
      // v: LDS-bounce transpose -> coalesced [b][h][d][t] stores.
      // Wave-private 8 KB scratch ([64 d][64 t] bf16, 128B rows, 16B-XOR swizzle).
      char* scb = (w < 2) ? ((char*)sA + w * 8192) : ((char*)sB + (w - 2) * 8192);
#pragma unroll
      for (int j = 0; j < 4; ++j) {
        const int dl = j * 16 + lr;                  // local d 0..63
        const float bv = bias2[(n0 + wc * 64 + dl) & 1023];
#pragma unroll
        for (int i = 0; i < 4; ++i) {
          ushort4 pk;
          pk.x = bfbits(acc[i][j][0] + bv);
          pk.y = bfbits(acc[i][j][1] + bv);
          pk.z = bfbits(acc[i][j][2] + bv);
          pk.w = bfbits(acc[i][j][3] + bv);
          *(ushort4*)(scb + dl * 128 + (((i * 16 + lk * 4) * 2) ^ ((dl & 7) << 4))) = pk;
        }
      }
      asm volatile("s_waitcnt lgkmcnt(0)" ::: "memory");
      const int hh = ((n0 + wc * 64) & 1023) >> 6;   // one head per wave
      const int bidx = (m0 + wr * 64) >> 11;
      const int tb = (m0 + wr * 64) & 2047;
      const int c = l & 7;                           // 8-elem t-chunk within 64
#pragma unroll
      for (int g = 0; g < 8; ++g) {
        const int dl = g * 8 + (l >> 3);
        u16x8 val = *(const u16x8*)(scb + dl * 128 + ((c * 16) ^ ((dl & 7) << 4)));
        *(u16x8*)&o2[(((size_t)(bidx * HH + hh)) * HDD + dl) * TT + tb + c * 8] = val;
      }
    }
  } else if constexpr (EPI == 1) {
    float bv4[4];
#pragma unroll
    for (int j = 0; j < 4; ++j)
      bv4[j] = addb ? bias0[n0 + wc * 64 + j * 16 + lr] : 0.f;
#pragma unroll
    for (int i = 0; i < 4; ++i) {
      const int mrow = m0 + wr * 64 + i * 16 + lk * 4;
#pragma unroll
      for (int r = 0; r < 4; ++r) {
        float* rowp = part + (size_t)(mrow + r) * N + n0 + wc * 64;
#pragma unroll
        for (int j = 0; j < 4; ++j)   // 4 x 64B chunks back-to-back = 2 full lines
          rowp[j * 16 + lr] = acc[i][j][r] + bv4[j];
      }
    }
  } else {  // EPI == 2: GELU
    float bv4[4];
#pragma unroll
    for (int j = 0; j < 4; ++j) bv4[j] = bias0[n0 + wc * 64 + j * 16 + lr];
#pragma unroll
    for (int i = 0; i < 4; ++i) {
      const int mrow = m0 + wr * 64 + i * 16 + lk * 4;
#pragma unroll
      for (int r = 0; r < 4; ++r) {
        bf16* rowp = o0 + (size_t)(mrow + r) * N + n0 + wc * 64;
#pragma unroll
        for (int j = 0; j < 4; ++j) {
          const float x = acc[i][j][r] + bv4[j];
          rowp[j * 16 + lr] = (bf16)(0.5f * x * (1.f + erff(x * 0.70710678f)));
        }
      }
    }
  }
  (void)M;
}

// ---------- causal flash attention (R9 staging; exp2-domain softmax) ----------
// Q,K: [b][h][t][d] (Q pre-scaled by 0.125*log2e); Vt: [b][h][d][t]; O bf16.
// 1D grid of 512, XCD-swizzled. Block = 4 waves x 32 q-rows, pair {xt, 15-xt}.
// Masking applied only on the single diagonal tile per (wave,qi).
__global__ __launch_bounds__(256) void attn_fwd(
    const bf16* __restrict__ Q, const bf16* __restrict__ Kk,
    const bf16* __restrict__ Vt, bf16* __restrict__ O)
{
  const int wk = xcd_swz((int)blockIdx.x, (int)gridDim.x);
  const int bh = wk >> 3;
  const int xt = wk & 7;
  const int tid = threadIdx.x;
  const int w = tid >> 6, l = tid & 63;
  const int lr = l & 15, lk = l >> 4;
  const int bidx = bh >> 4, hh = bh & 15;

  const bf16* Qp = Q  + (size_t)bh * (TT * HDD);
  const bf16* Kp = Kk + (size_t)bh * (TT * HDD);
  const bf16* Vp = Vt + (size_t)bh * (HDD * TT);

  __shared__ __align__(16) bf16 sK[64 * 64];
  __shared__ __align__(16) bf16 sV[64 * 64];
  __shared__ __align__(16) bf16 sP[4][16 * 64];
  bf16* sPw = &sP[w][0];

  const int swz = (lr & 7) * 8;       // element-offset XOR for LDS reads
  const int srow = tid >> 3;                        // staging source row 0..31
  const int scol = (((tid & 7) ^ (srow & 7)) << 3); // inverse-swizzled source col
  const int sdst = tid << 3;                        // linear LDS dest (elements)

  for (int half = 0; half < 2; ++half) {
    const int qtile = (half == 0) ? xt : (15 - xt);
    const int q0 = qtile * 128;

    bf16x8 qf[2][2];
#pragma unroll
    for (int qi = 0; qi < 2; ++qi)
#pragma unroll
      for (int dk = 0; dk < 2; ++dk)
        qf[qi][dk] = *(const bf16x8*)&Qp[(size_t)(q0 + w * 32 + qi * 16 + lr) * HDD + dk * 32 + lk * 8];

    f32x4 accO[2][4] = {};
    float mrun[2] = {-__builtin_inff(), -__builtin_inff()};
    float lrun[2] = {0.f, 0.f};
    const int wqmax = q0 + w * 32 + 31;
    const int kvend = q0 + 128;

    for (int kv = 0; kv < kvend; kv += 64) {
      __syncthreads();   // previous LDS readers done (and half-boundary safety)
#pragma unroll
      for (int i = 0; i < 2; ++i) {
        GLDS(Kp + (size_t)(kv + srow + i * 32) * HDD + scol, sK + sdst + i * 2048);
        GLDS(Vp + (size_t)(srow + i * 32) * TT + kv + scol, sV + sdst + i * 2048);
      }
      __syncthreads();   // staging complete

      if (kv <= wqmax) {
#pragma unroll
        for (int qi = 0; qi < 2; ++qi) {
          f32x4 st[4];
#pragma unroll
          for (int kt = 0; kt < 4; ++kt) {
            f32x4 z = {0.f, 0.f, 0.f, 0.f};
#pragma unroll
            for (int dk = 0; dk < 2; ++dk) {
              bf16x8 kf = *(const bf16x8*)&sK[(kt * 16 + lr) * 64 + ((dk * 32 + lk * 8) ^ swz)];
              z = __builtin_amdgcn_mfma_f32_16x16x32_bf16(kf, qf[qi][dk], z, 0, 0, 0);
            }
            st[kt] = z;
          }
          const int qabs_base = q0 + w * 32 + qi * 16;
          float pm = -__builtin_inff();
          if (kv + 63 > qabs_base) {
            // diagonal tile: per-element causal mask (scores already scaled)
            const int qabs = qabs_base + lr;
#pragma unroll
            for (int kt = 0; kt < 4; ++kt)
#pragma unroll
              for (int r = 0; r < 4; ++r) {
                const int kvabs = kv + kt * 16 + lk * 4 + r;
                float val = (kvabs > qabs) ? -__builtin_inff() : st[kt][r];
                st[kt][r] = val;
                pm = fmaxf(pm, val);
              }
          } else {
#pragma unroll
            for (int kt = 0; kt < 4; ++kt)
#pragma unroll
              for (int r = 0; r < 4; ++r) pm = fmaxf(pm, st[kt][r]);
          }
          pm = fmaxf(pm, __shfl_xor(pm, 16));
          pm = fmaxf(pm, __shfl_xor(pm, 32));
          const float mnew = fmaxf(mrun[qi], pm);
          const float alpha = exp2f(mrun[qi] - mnew);
          mrun[qi] = mnew;
          float psum = 0.f;
#pragma unroll
          for (int kt = 0; kt < 4; ++kt) {
            const float p0v = exp2f(st[kt][0] - mnew);
            const float p1v = exp2f(st[kt][1] - mnew);
            const float p2v = exp2f(st[kt][2] - mnew);
            const float p3v = exp2f(st[kt][3] - mnew);
            psum += p0v + p1v + p2v + p3v;
            ushort4 pk;
            pk.x = bfbits(p0v); pk.y = bfbits(p1v); pk.z = bfbits(p2v); pk.w = bfbits(p3v);
            *(ushort4*)&sPw[lr * 64 + ((kt * 16 + lk * 4) ^ swz)] = pk;
          }
          psum += __shfl_xor(psum, 16);
          psum += __shfl_xor(psum, 32);
          lrun[qi] = lrun[qi] * alpha + psum;
          f32x4 al4;
#pragma unroll
          for (int r = 0; r < 4; ++r) al4[r] = __shfl(alpha, lk * 4 + r);
#pragma unroll
          for (int dj = 0; dj < 4; ++dj) accO[qi][dj] *= al4;
#pragma unroll
          for (int kt2 = 0; kt2 < 2; ++kt2) {
            bf16x8 pf = *(const bf16x8*)&sPw[lr * 64 + ((kt2 * 32 + lk * 8) ^ swz)];
#pragma unroll
            for (int dj = 0; dj < 4; ++dj) {
              bf16x8 vf = *(const bf16x8*)&sV[(dj * 16 + lr) * 64 + ((kt2 * 32 + lk * 8) ^ swz)];
              accO[qi][dj] = __builtin_amdgcn_mfma_f32_16x16x32_bf16(pf, vf, accO[qi][dj], 0, 0, 0);
            }
          }
        }
      }
    }

#pragma unroll
    for (int qi = 0; qi < 2; ++qi) {
      const float linv = 1.f / lrun[qi];
      f32x4 li4;
#pragma unroll
      for (int r = 0; r < 4; ++r) li4[r] = __shfl(linv, lk * 4 + r);
      const int tbase = q0 + w * 32 + qi * 16 + lk * 4;
#pragma unroll
      for (int dj = 0; dj < 4; ++dj)
#pragma unroll
        for (int r = 0; r < 4; ++r)
          O[((size_t)bidx * TT + tbase + r) * CC + hh * 64 + dj * 16 + lr] =
              (bf16)(accO[qi][dj][r] * li4[r]);
    }
  }
}

extern "C" void kernel_launch(void* const* d_in, const int* in_sizes, int n_in,
                              void* d_out, int out_size, void* d_ws, size_t ws_size,
                              hipStream_t stream)
{
  const float* x    = (const float*)d_in[0];
  const float* ln1g = (const float*)d_in[1];
  const float* ln1b = (const float*)d_in[2];
  const float* ln2g = (const float*)d_in[3];
  const float* ln2b = (const float*)d_in[4];
  const float* wq   = (const float*)d_in[5];
  const float* bq   = (const float*)d_in[6];
  const float* wk   = (const float*)d_in[7];
  const float* bk   = (const float*)d_in[8];
  const float* wv   = (const float*)d_in[9];
  const float* bvv  = (const float*)d_in[10];
  const float* wo   = (const float*)d_in[11];
  const float* bo   = (const float*)d_in[12];
  const float* w1   = (const float*)d_in[13];
  const float* b1   = (const float*)d_in[14];
  const float* w2   = (const float*)d_in[15];
  const float* b2   = (const float*)d_in[16];

  float* h = (float*)d_out;  // fp32 residual stream lives in d_out
  bf16* ws = (bf16*)d_ws;
  bf16* wqkvT = ws;                                   // [L][3][C][C]
  bf16* woT   = wqkvT + (size_t)LL * 3 * CC * CC;     // [L][C][C]
  bf16* w1T   = woT + (size_t)LL * CC * CC;           // [L][DFF][C]
  bf16* w2T   = w1T + (size_t)LL * CC * DFFx;         // [L][C][DFF]
  bf16* hn    = w2T + (size_t)LL * CC * DFFx;         // [M][C]
  bf16* qb    = hn + (size_t)MMx * CC;                // [b][h][t][d]
  bf16* kb    = qb + (size_t)MMx * CC;
  bf16* vt    = kb + (size_t)MMx * CC;                // [b][h][d][t]
  bf16* ab    = vt + (size_t)MMx * CC;                // [b][t][c]
  bf16* mid   = ab + (size_t)MMx * CC;                // [M][DFF]

  // split-K partial buffers (fp32, 32 MB each), in dead regions:
  float* pw0 = (float*)mid;                 // wo partials live in mid (dead then)
  float* pw1 = (float*)mid + (size_t)MMx * CC;
  float* pm0 = (float*)qb;                  // w2 partials live in qb..ab (dead then)
  float* pm1 = (float*)vt;

  hipMemcpyAsync(h, x, (size_t)MMx * CC * sizeof(float), hipMemcpyDeviceToDevice, stream);

  dim3 tb(32, 8);
  transpose_cast<<<dim3(CC / 32, CC / 32, LL), tb, 0, stream>>>(wq, wqkvT, CC, CC, (long)CC * CC, (long)3 * CC * CC);
  transpose_cast<<<dim3(CC / 32, CC / 32, LL), tb, 0, stream>>>(wk, wqkvT + CC * CC, CC, CC, (long)CC * CC, (long)3 * CC * CC);
  transpose_cast<<<dim3(CC / 32, CC / 32, LL), tb, 0, stream>>>(wv, wqkvT + 2 * CC * CC, CC, CC, (long)CC * CC, (long)3 * CC * CC);
  transpose_cast<<<dim3(CC / 32, CC / 32, LL), tb, 0, stream>>>(wo, woT, CC, CC, (long)CC * CC, (long)CC * CC);
  transpose_cast<<<dim3(DFFx / 32, CC / 32, LL), tb, 0, stream>>>(w1, w1T, CC, DFFx, (long)CC * DFFx, (long)CC * DFFx);
  transpose_cast<<<dim3(CC / 32, DFFx / 32, LL), tb, 0, stream>>>(w2, w2T, DFFx, CC, (long)CC * DFFx, (long)CC * DFFx);

  for (int li = 0; li < LL; ++li) {
    // ln1 (fused with previous layer's w2 combine when li > 0)
    if (li == 0)
      ln_cmb<<<MMx, 256, 0, stream>>>(h, nullptr, nullptr, ln1g, ln1b, hn);
    else
      ln_cmb<<<MMx, 256, 0, stream>>>(h, pm0, pm1, ln1g + li * CC, ln1b + li * CC, hn);
    gemm128<0><<<(3 * CC / 128) * (MMx / 128), 256, 0, stream>>>(
        hn, wqkvT + (size_t)li * 3 * CC * CC, bq + li * CC, bk + li * CC, bvv + li * CC,
        qb, kb, vt, nullptr, nullptr, MMx, 3 * CC, CC, CC);
    attn_fwd<<<8 * BBx * HH, 256, 0, stream>>>(qb, kb, vt, ab);
    // wo split-K=2 -> partials in mid
    gemm128<1><<<2 * (CC / 128) * (MMx / 128), 256, 0, stream>>>(
        ab, woT + (size_t)li * CC * CC, bo + li * CC, nullptr, nullptr,
        nullptr, nullptr, nullptr, pw0, pw1, MMx, CC, CC / 2, CC);
    // ln2 fused with wo combine
    ln_cmb<<<MMx, 256, 0, stream>>>(h, pw0, pw1, ln2g + li * CC, ln2b + li * CC, hn);
    gemm128<2><<<(DFFx / 128) * (MMx / 128), 256, 0, stream>>>(
        hn, w1T + (size_t)li * CC * DFFx, b1 + li * DFFx, nullptr, nullptr,
        mid, nullptr, nullptr, nullptr, nullptr, MMx, DFFx, CC, CC);
    // w2 split-K=2 -> partials in qb/vt regions
    gemm128<1><<<2 * (CC / 128) * (MMx / 128), 256, 0, stream>>>(
        mid, w2T + (size_t)li * CC * DFFx, b2 + li * CC, nullptr, nullptr,
        nullptr, nullptr, nullptr, pm0, pm1, MMx, CC, DFFx / 2, DFFx);
  }
  // final combine (no LN)
  ln_cmb<<<MMx, 256, 0, stream>>>(h, pm0, pm1, nullptr, nullptr, nullptr);
  (void)in_sizes; (void)n_in; (void)out_size; (void)ws_size;
}

// Round 13
// 3269.171 us; speedup vs baseline: 1.0966x; 1.0353x over previous
//
#include <hip/hip_runtime.h>
#include <hip/hip_bf16.h>

#define LL 8
#define BBx 4
#define TT 2048
#define CC 1024
#define HH 16
#define HDD 64
#define DFFx 4096
#define MMx 8192  // B*T

typedef __bf16 bf16;
typedef __attribute__((ext_vector_type(8))) __bf16 bf16x8;
typedef __attribute__((ext_vector_type(4))) __bf16 bf16x4;
typedef __attribute__((ext_vector_type(4))) float f32x4;
typedef __attribute__((ext_vector_type(8))) unsigned short u16x8;

#define QSCALE 0.18033688f  // 0.125 * log2(e): Q pre-scaled -> softmax in exp2 domain

__device__ __forceinline__ unsigned short bfbits(float v) {
  return __builtin_bit_cast(unsigned short, (__bf16)v);
}

// native v_exp_f32 (2^x). exp2f() w/o fast-math is an ocml call (~10 VALU ops);
// this is 1 transcendental instruction.
__device__ __forceinline__ float fexp2(float x) {
#if __has_builtin(__builtin_amdgcn_exp2f)
  return __builtin_amdgcn_exp2f(x);
#else
  float r;
  asm volatile("v_exp_f32 %0, %1\n\ts_nop 0" : "=v"(r) : "v"(x));
  return r;
#endif
}

// XCD-chunked bijective swizzle (T1): nwg % 8 == 0 required.
__device__ __forceinline__ int xcd_swz(int id, int nwg) {
  return (id & 7) * (nwg >> 3) + (id >> 3);
}

#define GLDS(gp, lp) __builtin_amdgcn_global_load_lds( \
    (const __attribute__((address_space(1))) void*)(gp), \
    (__attribute__((address_space(3))) void*)(lp), 16, 0, 0)

// ---------- weight transpose + cast:  W[z][K][N] fp32 -> Wt[z][N][K] bf16 ----------
__global__ __launch_bounds__(256) void transpose_cast(
    const float* __restrict__ W, bf16* __restrict__ Wt,
    int K, int N, long srcStride, long dstStride)
{
  __shared__ float tile[32][33];
  const float* Wl = W + (size_t)blockIdx.z * srcStride;
  bf16* Wtl = Wt + (size_t)blockIdx.z * dstStride;
  const int n0 = blockIdx.x * 32, k0 = blockIdx.y * 32;
  const int tx = threadIdx.x, ty = threadIdx.y;
#pragma unroll
  for (int i = 0; i < 32; i += 8)
    tile[ty + i][tx] = Wl[(size_t)(k0 + ty + i) * N + n0 + tx];
  __syncthreads();
#pragma unroll
  for (int i = 0; i < 32; i += 8)
    Wtl[(size_t)(n0 + ty + i) * K + k0 + tx] = (bf16)tile[tx][ty + i];
}

// ---------- layernorm (+ optional split-K combine) fp32 -> bf16 ----------
// h_new = h + p0 + p1 (bias pre-folded into p0); out = LN(h_new) if out != null.
__global__ __launch_bounds__(256) void ln_cmb(
    float* __restrict__ h, const float* __restrict__ p0, const float* __restrict__ p1,
    const float* __restrict__ gamma, const float* __restrict__ beta,
    bf16* __restrict__ out)
{
  const int row = blockIdx.x, tid = threadIdx.x;
  const size_t base = (size_t)row * CC + tid * 4;
  float4 v = *(const float4*)(h + base);
  if (p0) {
    const float4 a = *(const float4*)(p0 + base);
    const float4 b = *(const float4*)(p1 + base);
    v.x += a.x + b.x; v.y += a.y + b.y; v.z += a.z + b.z; v.w += a.w + b.w;
    *(float4*)(h + base) = v;
  }
  if (!out) return;
  float s  = v.x + v.y + v.z + v.w;
  float ss = v.x * v.x + v.y * v.y + v.z * v.z + v.w * v.w;
#pragma unroll
  for (int o = 32; o >= 1; o >>= 1) {
    s  += __shfl_xor(s, o);
    ss += __shfl_xor(ss, o);
  }
  __shared__ float rs[4], rss[4];
  const int w = tid >> 6, l = tid & 63;
  if (l == 0) { rs[w] = s; rss[w] = ss; }
  __syncthreads();
  s  = rs[0] + rs[1] + rs[2] + rs[3];
  ss = rss[0] + rss[1] + rss[2] + rss[3];
  const float mu = s * (1.f / CC);
  const float rstd = rsqrtf(ss * (1.f / CC) - mu * mu + 1e-5f);
  const float4 g  = *(const float4*)(gamma + tid * 4);
  const float4 be = *(const float4*)(beta + tid * 4);
  bf16x4 o4;
  o4[0] = (bf16)((v.x - mu) * rstd * g.x + be.x);
  o4[1] = (bf16)((v.y - mu) * rstd * g.y + be.y);
  o4[2] = (bf16)((v.z - mu) * rstd * g.z + be.z);
  o4[3] = (bf16)((v.w - mu) * rstd * g.w + be.w);
  *(bf16x4*)(out + (size_t)row * CC + tid * 4) = o4;
}

// ---------- 128x128 GEMM, m97 structure: single-buffer, 2 barriers/K-tile ----------
// 256 thr = 4 waves (2M x 2N), wave tile 64x64, 32 KB LDS -> 4 blocks/CU (split-K
// keeps grids >= 1024 so 4 blocks/CU are actually resident; m114 overlap).
// 1D grid, XCD-chunked swizzle. j-innermost line-complete stores.
// EPI 0: fused QKV (q pre-scaled by QSCALE); EPI 1: split-K=2 fp32 partial write;
// EPI 2: GELU.
template<int EPI>
__global__ __launch_bounds__(256, 4) void gemm128(
    const bf16* __restrict__ A, const bf16* __restrict__ Bt,
    const float* __restrict__ bias0, const float* __restrict__ bias1,
    const float* __restrict__ bias2,
    bf16* __restrict__ o0, bf16* __restrict__ o1, bf16* __restrict__ o2,
    float* __restrict__ p0, float* __restrict__ p1,
    int M, int N, int K, int lda)
{
  __shared__ __align__(16) bf16 sA[128 * 64];
  __shared__ __align__(16) bf16 sB[128 * 64];
  const int nx = N >> 7;
  int wk = xcd_swz((int)blockIdx.x, (int)gridDim.x);
  int koff = 0;
  float* part = p0;
  bool addb = true;
  if constexpr (EPI == 1) {
    const int tiles = nx * (M >> 7);
    const int ks = wk / tiles;
    wk -= ks * tiles;
    koff = ks * K;
    addb = (ks == 0);
    part = ks ? p1 : p0;
  }
  const int m0 = (wk / nx) * 128;
  const int n0 = (wk % nx) * 128;
  const int tid = threadIdx.x;
  const int w = tid >> 6, l = tid & 63;
  const int wr = w >> 1, wc = w & 1;
  const int lr = l & 15, lk = l >> 4;

  f32x4 acc[4][4] = {};
  const int NT = K >> 6;

  for (int kt = 0; kt < NT; ++kt) {
#pragma unroll
    for (int i = 0; i < 4; ++i) {
      const int e = (tid << 4) + (i << 12);   // linear LDS byte offset
      const int ro = e >> 7, co = (e & 127) >> 1;
      GLDS(A + (size_t)(m0 + ro) * lda + kt * 64 + koff + co, sA + (e >> 1));
      GLDS(Bt + (size_t)(n0 + ro) * lda + kt * 64 + koff + co, sB + (e >> 1));
    }
    __syncthreads();
#pragma unroll
    for (int kk = 0; kk < 2; ++kk) {
      bf16x8 af[4], bfr[4];
#pragma unroll
      for (int i = 0; i < 4; ++i)
        af[i] = *(const bf16x8*)&sA[(wr * 64 + i * 16 + lr) * 64 + kk * 32 + lk * 8];
#pragma unroll
      for (int j = 0; j < 4; ++j)
        bfr[j] = *(const bf16x8*)&sB[(wc * 64 + j * 16 + lr) * 64 + kk * 32 + lk * 8];
#pragma unroll
      for (int i = 0; i < 4; ++i)
#pragma unroll
        for (int j = 0; j < 4; ++j)
          acc[i][j] = __builtin_amdgcn_mfma_f32_16x16x32_bf16(af[i], bfr[j], acc[i][j], 0, 0, 0);
    }
    __syncthreads();
  }

  if constexpr (EPI == 0) {
    const int seg = n0 >> 10;
    const float* bp = (seg == 0) ? bias0 : (seg == 1 ? bias1 : bias2);
    if (seg < 2) {
      const float qs = (seg == 0) ? QSCALE : 1.0f;   // pre-scale q for exp2 softmax
      float bv4[4];
#pragma unroll
      for (int j = 0; j < 4; ++j) bv4[j] = bp[(n0 + wc * 64 + j * 16 + lr) & 1023];
      const int hh = ((n0 + wc * 64) & 1023) >> 6;
      bf16* dst = (seg == 0) ? o0 : o1;
#pragma unroll
      for (int i = 0; i < 4; ++i) {
        const int mrow = m0 + wr * 64 + i * 16 + lk * 4;
        const int bidx = mrow >> 11, t = mrow & 2047;
#pragma unroll
        for (int r = 0; r < 4; ++r) {
          bf16* rowp = dst + (((size_t)(bidx * HH + hh)) * TT + t + r) * HDD;
#pragma unroll
          for (int j = 0; j < 4; ++j)   // 4 x 32B chunks back-to-back = full 128B line
            rowp[j * 16 + lr] = (bf16)((acc[i][j][r] + bv4[j]) * qs);
        }
      }
    } else {
      // v: LDS-bounce transpose -> coalesced [b][h][d][t] stores.
      // Wave-private 8 KB scratch ([64 d][64 t] bf16, 128B rows, 16B-XOR swizzle).
      char* scb = (w < 2) ? ((char*)sA + w * 8192) : ((char*)sB + (w - 2) * 8192);
#pragma unroll
      for (int j = 0; j < 4; ++j) {
        const int dl = j * 16 + lr;                  // local d 0..63
        const float bv = bias2[(n0 + wc * 64 + dl) & 1023];
#pragma unroll
        for (int i = 0; i < 4; ++i) {
          ushort4 pk;
          pk.x = bfbits(acc[i][j][0] + bv);
          pk.y = bfbits(acc[i][j][1] + bv);
          pk.z = bfbits(acc[i][j][2] + bv);
          pk.w = bfbits(acc[i][j][3] + bv);
          *(ushort4*)(scb + dl * 128 + (((i * 16 + lk * 4) * 2) ^ ((dl & 7) << 4))) = pk;
        }
      }
      asm volatile("s_waitcnt lgkmcnt(0)" ::: "memory");
      const int hh = ((n0 + wc * 64) & 1023) >> 6;   // one head per wave
      const int bidx = (m0 + wr * 64) >> 11;
      const int tb = (m0 + wr * 64) & 2047;
      const int c = l & 7;                           // 8-elem t-chunk within 64
#pragma unroll
      for (int g = 0; g < 8; ++g) {
        const int dl = g * 8 + (l >> 3);
        u16x8 val = *(const u16x8*)(scb + dl * 128 + ((c * 16) ^ ((dl & 7) << 4)));
        *(u16x8*)&o2[(((size_t)(bidx * HH + hh)) * HDD + dl) * TT + tb + c * 8] = val;
      }
    }
  } else if constexpr (EPI == 1) {
    float bv4[4];
#pragma unroll
    for (int j = 0; j < 4; ++j)
      bv4[j] = addb ? bias0[n0 + wc * 64 + j * 16 + lr] : 0.f;
#pragma unroll
    for (int i = 0; i < 4; ++i) {
      const int mrow = m0 + wr * 64 + i * 16 + lk * 4;
#pragma unroll
      for (int r = 0; r < 4; ++r) {
        float* rowp = part + (size_t)(mrow + r) * N + n0 + wc * 64;
#pragma unroll
        for (int j = 0; j < 4; ++j)   // 4 x 64B chunks back-to-back = 2 full lines
          rowp[j * 16 + lr] = acc[i][j][r] + bv4[j];
      }
    }
  } else {  // EPI == 2: GELU
    float bv4[4];
#pragma unroll
    for (int j = 0; j < 4; ++j) bv4[j] = bias0[n0 + wc * 64 + j * 16 + lr];
#pragma unroll
    for (int i = 0; i < 4; ++i) {
      const int mrow = m0 + wr * 64 + i * 16 + lk * 4;
#pragma unroll
      for (int r = 0; r < 4; ++r) {
        bf16* rowp = o0 + (size_t)(mrow + r) * N + n0 + wc * 64;
#pragma unroll
        for (int j = 0; j < 4; ++j) {
          const float x = acc[i][j][r] + bv4[j];
          rowp[j * 16 + lr] = (bf16)(0.5f * x * (1.f + erff(x * 0.70710678f)));
        }
      }
    }
  }
  (void)M;
}

// ---------- causal flash attention (R9 staging; native-exp2 softmax) ----------
// Q,K: [b][h][t][d] (Q pre-scaled by 0.125*log2e); Vt: [b][h][d][t]; O bf16.
// 1D grid of 512, XCD-swizzled. Block = 4 waves x 32 q-rows, pair {xt, 15-xt}.
// Masking applied only on the single diagonal tile per (wave,qi).
__global__ __launch_bounds__(256) void attn_fwd(
    const bf16* __restrict__ Q, const bf16* __restrict__ Kk,
    const bf16* __restrict__ Vt, bf16* __restrict__ O)
{
  const int wk = xcd_swz((int)blockIdx.x, (int)gridDim.x);
  const int bh = wk >> 3;
  const int xt = wk & 7;
  const int tid = threadIdx.x;
  const int w = tid >> 6, l = tid & 63;
  const int lr = l & 15, lk = l >> 4;
  const int bidx = bh >> 4, hh = bh & 15;

  const bf16* Qp = Q  + (size_t)bh * (TT * HDD);
  const bf16* Kp = Kk + (size_t)bh * (TT * HDD);
  const bf16* Vp = Vt + (size_t)bh * (HDD * TT);

  __shared__ __align__(16) bf16 sK[64 * 64];
  __shared__ __align__(16) bf16 sV[64 * 64];
  __shared__ __align__(16) bf16 sP[4][16 * 64];
  bf16* sPw = &sP[w][0];

  const int swz = (lr & 7) * 8;       // element-offset XOR for LDS reads
  const int srow = tid >> 3;                        // staging source row 0..31
  const int scol = (((tid & 7) ^ (srow & 7)) << 3); // inverse-swizzled source col
  const int sdst = tid << 3;                        // linear LDS dest (elements)

  for (int half = 0; half < 2; ++half) {
    const int qtile = (half == 0) ? xt : (15 - xt);
    const int q0 = qtile * 128;

    bf16x8 qf[2][2];
#pragma unroll
    for (int qi = 0; qi < 2; ++qi)
#pragma unroll
      for (int dk = 0; dk < 2; ++dk)
        qf[qi][dk] = *(const bf16x8*)&Qp[(size_t)(q0 + w * 32 + qi * 16 + lr) * HDD + dk * 32 + lk * 8];

    f32x4 accO[2][4] = {};
    float mrun[2] = {-__builtin_inff(), -__builtin_inff()};
    float lrun[2] = {0.f, 0.f};
    const int wqmax = q0 + w * 32 + 31;
    const int kvend = q0 + 128;

    for (int kv = 0; kv < kvend; kv += 64) {
      __syncthreads();   // previous LDS readers done (and half-boundary safety)
#pragma unroll
      for (int i = 0; i < 2; ++i) {
        GLDS(Kp + (size_t)(kv + srow + i * 32) * HDD + scol, sK + sdst + i * 2048);
        GLDS(Vp + (size_t)(srow + i * 32) * TT + kv + scol, sV + sdst + i * 2048);
      }
      __syncthreads();   // staging complete

      if (kv <= wqmax) {
#pragma unroll
        for (int qi = 0; qi < 2; ++qi) {
          f32x4 st[4];
#pragma unroll
          for (int kt = 0; kt < 4; ++kt) {
            f32x4 z = {0.f, 0.f, 0.f, 0.f};
#pragma unroll
            for (int dk = 0; dk < 2; ++dk) {
              bf16x8 kf = *(const bf16x8*)&sK[(kt * 16 + lr) * 64 + ((dk * 32 + lk * 8) ^ swz)];
              z = __builtin_amdgcn_mfma_f32_16x16x32_bf16(kf, qf[qi][dk], z, 0, 0, 0);
            }
            st[kt] = z;
          }
          const int qabs_base = q0 + w * 32 + qi * 16;
          float pm = -__builtin_inff();
          if (kv + 63 > qabs_base) {
            // diagonal tile: per-element causal mask (scores already scaled)
            const int qabs = qabs_base + lr;
#pragma unroll
            for (int kt = 0; kt < 4; ++kt)
#pragma unroll
              for (int r = 0; r < 4; ++r) {
                const int kvabs = kv + kt * 16 + lk * 4 + r;
                float val = (kvabs > qabs) ? -__builtin_inff() : st[kt][r];
                st[kt][r] = val;
                pm = fmaxf(pm, val);
              }
          } else {
#pragma unroll
            for (int kt = 0; kt < 4; ++kt)
#pragma unroll
              for (int r = 0; r < 4; ++r) pm = fmaxf(pm, st[kt][r]);
          }
          pm = fmaxf(pm, __shfl_xor(pm, 16));
          pm = fmaxf(pm, __shfl_xor(pm, 32));
          const float mnew = fmaxf(mrun[qi], pm);
          const float alpha = fexp2(mrun[qi] - mnew);
          mrun[qi] = mnew;
          float psum = 0.f;
#pragma unroll
          for (int kt = 0; kt < 4; ++kt) {
            const float p0v = fexp2(st[kt][0] - mnew);
            const float p1v = fexp2(st[kt][1] - mnew);
            const float p2v = fexp2(st[kt][2] - mnew);
            const float p3v = fexp2(st[kt][3] - mnew);
            psum += p0v + p1v + p2v + p3v;
            ushort4 pk;
            pk.x = bfbits(p0v); pk.y = bfbits(p1v); pk.z = bfbits(p2v); pk.w = bfbits(p3v);
            *(ushort4*)&sPw[lr * 64 + ((kt * 16 + lk * 4) ^ swz)] = pk;
          }
          psum += __shfl_xor(psum, 16);
          psum += __shfl_xor(psum, 32);
          lrun[qi] = lrun[qi] * alpha + psum;
          f32x4 al4;
#pragma unroll
          for (int r = 0; r < 4; ++r) al4[r] = __shfl(alpha, lk * 4 + r);
#pragma unroll
          for (int dj = 0; dj < 4; ++dj) accO[qi][dj] *= al4;
#pragma unroll
          for (int kt2 = 0; kt2 < 2; ++kt2) {
            bf16x8 pf = *(const bf16x8*)&sPw[lr * 64 + ((kt2 * 32 + lk * 8) ^ swz)];
#pragma unroll
            for (int dj = 0; dj < 4; ++dj) {
              bf16x8 vf = *(const bf16x8*)&sV[(dj * 16 + lr) * 64 + ((kt2 * 32 + lk * 8) ^ swz)];
              accO[qi][dj] = __builtin_amdgcn_mfma_f32_16x16x32_bf16(pf, vf, accO[qi][dj], 0, 0, 0);
            }
          }
        }
      }
    }

#pragma unroll
    for (int qi = 0; qi < 2; ++qi) {
      const float linv = 1.f / lrun[qi];
      f32x4 li4;
#pragma unroll
      for (int r = 0; r < 4; ++r) li4[r] = __shfl(linv, lk * 4 + r);
      const int tbase = q0 + w * 32 + qi * 16 + lk * 4;
#pragma unroll
      for (int dj = 0; dj < 4; ++dj)
#pragma unroll
        for (int r = 0; r < 4; ++r)
          O[((size_t)bidx * TT + tbase + r) * CC + hh * 64 + dj * 16 + lr] =
              (bf16)(accO[qi][dj][r] * li4[r]);
    }
  }
}

extern "C" void kernel_launch(void* const* d_in, const int* in_sizes, int n_in,
                              void* d_out, int out_size, void* d_ws, size_t ws_size,
                              hipStream_t stream)
{
  const float* x    = (const float*)d_in[0];
  const float* ln1g = (const float*)d_in[1];
  const float* ln1b = (const float*)d_in[2];
  const float* ln2g = (const float*)d_in[3];
  const float* ln2b = (const float*)d_in[4];
  const float* wq   = (const float*)d_in[5];
  const float* bq   = (const float*)d_in[6];
  const float* wk   = (const float*)d_in[7];
  const float* bk   = (const float*)d_in[8];
  const float* wv   = (const float*)d_in[9];
  const float* bvv  = (const float*)d_in[10];
  const float* wo   = (const float*)d_in[11];
  const float* bo   = (const float*)d_in[12];
  const float* w1   = (const float*)d_in[13];
  const float* b1   = (const float*)d_in[14];
  const float* w2   = (const float*)d_in[15];
  const float* b2   = (const float*)d_in[16];

  float* h = (float*)d_out;  // fp32 residual stream lives in d_out
  bf16* ws = (bf16*)d_ws;
  bf16* wqkvT = ws;                                   // [L][3][C][C]
  bf16* woT   = wqkvT + (size_t)LL * 3 * CC * CC;     // [L][C][C]
  bf16* w1T   = woT + (size_t)LL * CC * CC;           // [L][DFF][C]
  bf16* w2T   = w1T + (size_t)LL * CC * DFFx;         // [L][C][DFF]
  bf16* hn    = w2T + (size_t)LL * CC * DFFx;         // [M][C]
  bf16* qb    = hn + (size_t)MMx * CC;                // [b][h][t][d]
  bf16* kb    = qb + (size_t)MMx * CC;
  bf16* vt    = kb + (size_t)MMx * CC;                // [b][h][d][t]
  bf16* ab    = vt + (size_t)MMx * CC;                // [b][t][c]
  bf16* mid   = ab + (size_t)MMx * CC;                // [M][DFF]

  // split-K partial buffers (fp32, 32 MB each), in dead regions:
  float* pw0 = (float*)mid;                 // wo partials live in mid (dead then)
  float* pw1 = (float*)mid + (size_t)MMx * CC;
  float* pm0 = (float*)qb;                  // w2 partials live in qb..ab (dead then)
  float* pm1 = (float*)vt;

  hipMemcpyAsync(h, x, (size_t)MMx * CC * sizeof(float), hipMemcpyDeviceToDevice, stream);

  dim3 tb(32, 8);
  transpose_cast<<<dim3(CC / 32, CC / 32, LL), tb, 0, stream>>>(wq, wqkvT, CC, CC, (long)CC * CC, (long)3 * CC * CC);
  transpose_cast<<<dim3(CC / 32, CC / 32, LL), tb, 0, stream>>>(wk, wqkvT + CC * CC, CC, CC, (long)CC * CC, (long)3 * CC * CC);
  transpose_cast<<<dim3(CC / 32, CC / 32, LL), tb, 0, stream>>>(wv, wqkvT + 2 * CC * CC, CC, CC, (long)CC * CC, (long)3 * CC * CC);
  transpose_cast<<<dim3(CC / 32, CC / 32, LL), tb, 0, stream>>>(wo, woT, CC, CC, (long)CC * CC, (long)CC * CC);
  transpose_cast<<<dim3(DFFx / 32, CC / 32, LL), tb, 0, stream>>>(w1, w1T, CC, DFFx, (long)CC * DFFx, (long)CC * DFFx);
  transpose_cast<<<dim3(CC / 32, DFFx / 32, LL), tb, 0, stream>>>(w2, w2T, DFFx, CC, (long)CC * DFFx, (long)CC * DFFx);

  for (int li = 0; li < LL; ++li) {
    // ln1 (fused with previous layer's w2 combine when li > 0)
    if (li == 0)
      ln_cmb<<<MMx, 256, 0, stream>>>(h, nullptr, nullptr, ln1g, ln1b, hn);
    else
      ln_cmb<<<MMx, 256, 0, stream>>>(h, pm0, pm1, ln1g + li * CC, ln1b + li * CC, hn);
    gemm128<0><<<(3 * CC / 128) * (MMx / 128), 256, 0, stream>>>(
        hn, wqkvT + (size_t)li * 3 * CC * CC, bq + li * CC, bk + li * CC, bvv + li * CC,
        qb, kb, vt, nullptr, nullptr, MMx, 3 * CC, CC, CC);
    attn_fwd<<<8 * BBx * HH, 256, 0, stream>>>(qb, kb, vt, ab);
    // wo split-K=2 -> partials in mid
    gemm128<1><<<2 * (CC / 128) * (MMx / 128), 256, 0, stream>>>(
        ab, woT + (size_t)li * CC * CC, bo + li * CC, nullptr, nullptr,
        nullptr, nullptr, nullptr, pw0, pw1, MMx, CC, CC / 2, CC);
    // ln2 fused with wo combine
    ln_cmb<<<MMx, 256, 0, stream>>>(h, pw0, pw1, ln2g + li * CC, ln2b + li * CC, hn);
    gemm128<2><<<(DFFx / 128) * (MMx / 128), 256, 0, stream>>>(
        hn, w1T + (size_t)li * CC * DFFx, b1 + li * DFFx, nullptr, nullptr,
        mid, nullptr, nullptr, nullptr, nullptr, MMx, DFFx, CC, CC);
    // w2 split-K=2 -> partials in qb/vt regions
    gemm128<1><<<2 * (CC / 128) * (MMx / 128), 256, 0, stream>>>(
        mid, w2T + (size_t)li * CC * DFFx, b2 + li * CC, nullptr, nullptr,
        nullptr, nullptr, nullptr, pm0, pm1, MMx, CC, DFFx / 2, DFFx);
  }
  // final combine (no LN)
  ln_cmb<<<MMx, 256, 0, stream>>>(h, pm0, pm1, nullptr, nullptr, nullptr);
  (void)in_sizes; (void)n_in; (void)out_size; (void)ws_size;
}